// Round 1
// baseline (3676.964 us; speedup 1.0000x reference)
//
#include <hip/hip_runtime.h>

// ---------------- problem constants (match setup_inputs) ----------------
#define E0 506880
#define E1 30720
#define E2 2560
#define NN0 540672
#define NN1 33792
#define NN2 3072
#define NN3 512
#define F_IN 256
#define F_HID 1024
#define F_OUT 47

// ---------------- edge scatter: agg[dst] += feat[src], deg[dst] += 1 ----
// One wave (64 lanes) per edge; each lane handles F/64 floats as float4s.
__global__ __launch_bounds__(256) void scatter_edges(
    const float* __restrict__ feat, const int* __restrict__ src,
    const int* __restrict__ dst, float* __restrict__ agg,
    float* __restrict__ deg, int E, int F)
{
    int wave = (blockIdx.x * blockDim.x + threadIdx.x) >> 6;
    int lane = threadIdx.x & 63;
    if (wave >= E) return;
    int s = src[wave];
    int d = dst[wave];
    const float* fp = feat + (size_t)s * F;
    float*       ap = agg  + (size_t)d * F;
    int chunks = F >> 8;  // each chunk = 64 lanes * 4 floats = 256 floats
    for (int j = 0; j < chunks; ++j) {
        int off = (j << 8) + (lane << 2);
        float4 v = *(const float4*)(fp + off);
        atomicAdd(ap + off + 0, v.x);
        atomicAdd(ap + off + 1, v.y);
        atomicAdd(ap + off + 2, v.z);
        atomicAdd(ap + off + 3, v.w);
    }
    if (lane == 0) atomicAdd(deg + d, 1.0f);
}

// ---------------- fused dual-GEMM:  C = A1@W1 + (A2*invdeg)@W2 + b ------
// 128x128 tile, BK=16, 256 threads, 8x8 per-thread (2x2 sub-blocks of 4).
// Requires: M % 128 == 0, N % 128 == 0, K % 16 == 0. (N=1024 here.)
__global__ __launch_bounds__(256, 2) void sage_gemm128(
    const float* __restrict__ A1, const float* __restrict__ A2,
    const float* __restrict__ deg,
    const float* __restrict__ W1, const float* __restrict__ W2,
    const float* __restrict__ bias, float* __restrict__ C,
    int M, int N, int K, int relu)
{
    __shared__ float As[16][132];   // [k][row], 132-pad keeps rows 16B-aligned
    __shared__ float Wt[16][132];   // [k][col]

    const int tid  = threadIdx.x;
    const int row0 = blockIdx.x * 128;
    const int col0 = blockIdx.y * 128;
    const int tx = tid & 15;        // col group
    const int ty = tid >> 4;        // row group

    float acc[8][8];
    #pragma unroll
    for (int i = 0; i < 8; ++i)
        #pragma unroll
        for (int j = 0; j < 8; ++j) acc[i][j] = 0.0f;

    for (int pass = 0; pass < 2; ++pass) {
        const float* A = pass ? A2 : A1;
        const float* W = pass ? W2 : W1;
        for (int k0 = 0; k0 < K; k0 += 16) {
            // A tile: 128 rows x 16 k = 512 float4s -> 2 per thread
            #pragma unroll
            for (int q = 0; q < 2; ++q) {
                int f   = tid * 2 + q;
                int row = f >> 2;
                int kq  = (f & 3) << 2;
                float4 av = *(const float4*)(A + (size_t)(row0 + row) * K + k0 + kq);
                if (pass) {
                    float sc = 1.0f / fmaxf(deg[row0 + row], 1.0f);
                    av.x *= sc; av.y *= sc; av.z *= sc; av.w *= sc;
                }
                As[kq + 0][row] = av.x;
                As[kq + 1][row] = av.y;
                As[kq + 2][row] = av.z;
                As[kq + 3][row] = av.w;
            }
            // W tile: 16 k x 128 cols = 512 float4s -> 2 per thread
            #pragma unroll
            for (int q = 0; q < 2; ++q) {
                int f  = tid * 2 + q;
                int kk = f >> 5;
                int cq = (f & 31) << 2;
                float4 wv = *(const float4*)(W + (size_t)(k0 + kk) * N + col0 + cq);
                *(float4*)&Wt[kk][cq] = wv;
            }
            __syncthreads();
            #pragma unroll
            for (int k = 0; k < 16; ++k) {
                float4 a0 = *(const float4*)&As[k][ty << 2];
                float4 a1 = *(const float4*)&As[k][(ty << 2) + 64];
                float4 b0 = *(const float4*)&Wt[k][tx << 2];
                float4 b1 = *(const float4*)&Wt[k][(tx << 2) + 64];
                float ar[8] = {a0.x, a0.y, a0.z, a0.w, a1.x, a1.y, a1.z, a1.w};
                float br[8] = {b0.x, b0.y, b0.z, b0.w, b1.x, b1.y, b1.z, b1.w};
                #pragma unroll
                for (int i = 0; i < 8; ++i)
                    #pragma unroll
                    for (int j = 0; j < 8; ++j)
                        acc[i][j] = fmaf(ar[i], br[j], acc[i][j]);
            }
            __syncthreads();
        }
    }

    // epilogue: bias + optional ReLU, float4 stores (N % 4 == 0 guaranteed)
    #pragma unroll
    for (int i = 0; i < 8; ++i) {
        int r = row0 + ((i < 4) ? ((ty << 2) + i) : (64 + (ty << 2) + i - 4));
        #pragma unroll
        for (int jh = 0; jh < 2; ++jh) {
            int c = col0 + (tx << 2) + jh * 64;
            float4 v;
            v.x = acc[i][jh * 4 + 0] + bias[c + 0];
            v.y = acc[i][jh * 4 + 1] + bias[c + 1];
            v.z = acc[i][jh * 4 + 2] + bias[c + 2];
            v.w = acc[i][jh * 4 + 3] + bias[c + 3];
            if (relu) {
                v.x = fmaxf(v.x, 0.0f); v.y = fmaxf(v.y, 0.0f);
                v.z = fmaxf(v.z, 0.0f); v.w = fmaxf(v.w, 0.0f);
            }
            *(float4*)(C + (size_t)r * N + c) = v;
        }
    }
}

// ---------------- skinny GEMM for the final [512 x 47] layer ------------
// One wave per output row; lane c (< N) owns column c; K-loop accumulates.
__global__ __launch_bounds__(256) void skinny_gemm(
    const float* __restrict__ A1, const float* __restrict__ A2,
    const float* __restrict__ deg,
    const float* __restrict__ W1, const float* __restrict__ W2,
    const float* __restrict__ bias, float* __restrict__ C,
    int M, int N, int K, int relu)
{
    int wave = (blockIdx.x * blockDim.x + threadIdx.x) >> 6;
    int lane = threadIdx.x & 63;
    if (wave >= M || lane >= N) return;
    float s = 1.0f / fmaxf(deg[wave], 1.0f);
    const float* a1 = A1 + (size_t)wave * K;
    const float* a2 = A2 + (size_t)wave * K;
    float acc = 0.0f;
    #pragma unroll 8
    for (int k = 0; k < K; ++k) {
        acc = fmaf(a1[k], W1[(size_t)k * N + lane], acc);
        acc = fmaf(s * a2[k], W2[(size_t)k * N + lane], acc);
    }
    float v = acc + bias[lane];
    if (relu) v = fmaxf(v, 0.0f);
    C[(size_t)wave * N + lane] = v;
}

// ---------------- host side ---------------------------------------------
extern "C" void kernel_launch(void* const* d_in, const int* in_sizes, int n_in,
                              void* d_out, int out_size, void* d_ws, size_t ws_size,
                              hipStream_t stream)
{
    const float* x   = (const float*)d_in[0];
    const int* src0  = (const int*)d_in[1];
    const int* dst0  = (const int*)d_in[2];
    const int* src1  = (const int*)d_in[3];
    const int* dst1  = (const int*)d_in[4];
    const int* src2  = (const int*)d_in[5];
    const int* dst2  = (const int*)d_in[6];
    const float* Wself0  = (const float*)d_in[7];
    const float* Wneigh0 = (const float*)d_in[8];
    const float* b0      = (const float*)d_in[9];
    const float* Wself1  = (const float*)d_in[10];
    const float* Wneigh1 = (const float*)d_in[11];
    const float* b1      = (const float*)d_in[12];
    const float* Wself2  = (const float*)d_in[13];
    const float* Wneigh2 = (const float*)d_in[14];
    const float* b2      = (const float*)d_in[15];
    float* out = (float*)d_out;

    // workspace carve-up (floats). h0, h1 first; all zero-init buffers
    // (agg*, deg*) contiguous at the end -> single memset.
    float* ws = (float*)d_ws;
    size_t off = 0;
    float* h0   = ws + off; off += (size_t)NN1 * F_HID;   // 33792 x 1024
    float* h1   = ws + off; off += (size_t)NN2 * F_HID;   // 3072 x 1024
    float* zbase = ws + off;
    float* agg0 = ws + off; off += (size_t)NN1 * F_IN;    // 33792 x 256
    float* deg0 = ws + off; off += NN1;
    float* agg1 = ws + off; off += (size_t)NN2 * F_HID;   // 3072 x 1024
    float* deg1 = ws + off; off += NN2;
    float* agg2 = ws + off; off += (size_t)NN3 * F_HID;   // 512 x 1024
    float* deg2 = ws + off; off += NN3;
    size_t zbytes = (size_t)((ws + off) - zbase) * sizeof(float);

    hipMemsetAsync(zbase, 0, zbytes, stream);

    // Layer 0: aggregate x over E0 edges, then [33792,512]@[512,1024] + ReLU
    scatter_edges<<<dim3((E0 + 3) / 4), dim3(256), 0, stream>>>(
        x, src0, dst0, agg0, deg0, E0, F_IN);
    sage_gemm128<<<dim3(NN1 / 128, F_HID / 128), dim3(256), 0, stream>>>(
        x, agg0, deg0, Wself0, Wneigh0, b0, h0, NN1, F_HID, F_IN, 1);

    // Layer 1
    scatter_edges<<<dim3((E1 + 3) / 4), dim3(256), 0, stream>>>(
        h0, src1, dst1, agg1, deg1, E1, F_HID);
    sage_gemm128<<<dim3(NN2 / 128, F_HID / 128), dim3(256), 0, stream>>>(
        h0, agg1, deg1, Wself1, Wneigh1, b1, h1, NN2, F_HID, F_HID, 1);

    // Layer 2: [512, 2048] @ [2048, 47] -> d_out
    scatter_edges<<<dim3((E2 + 3) / 4), dim3(256), 0, stream>>>(
        h1, src2, dst2, agg2, deg2, E2, F_HID);
    skinny_gemm<<<dim3(NN3 / 4), dim3(256), 0, stream>>>(
        h1, agg2, deg2, Wself2, Wneigh2, b2, out, NN3, F_OUT, F_HID, 0);
}

// Round 2
// 1642.900 us; speedup vs baseline: 2.2381x; 2.2381x over previous
//
#include <hip/hip_runtime.h>

// ---------------- problem constants (match setup_inputs) ----------------
#define E0 506880
#define E1 30720
#define E2 2560
#define NN0 540672
#define NN1 33792
#define NN2 3072
#define NN3 512
#define F_IN 256
#define F_HID 1024
#define F_OUT 47

// ---------------- CSR build: counting sort of edges by dst --------------
__global__ __launch_bounds__(256) void count_dst(
    const int* __restrict__ dst, int* __restrict__ cnt, int E)
{
    int i = blockIdx.x * blockDim.x + threadIdx.x;
    if (i < E) atomicAdd(&cnt[dst[i]], 1);
}

// Single-block exclusive scan of cnt[0..n) -> cursor[0..n)
__global__ __launch_bounds__(1024) void scan_excl(
    const int* __restrict__ cnt, int* __restrict__ cursor, int n)
{
    __shared__ int part[1024];
    int t = threadIdx.x;
    int per = (n + 1023) >> 10;
    int lo = t * per;
    int hi = min(n, lo + per);
    int s = 0;
    for (int i = lo; i < hi; ++i) s += cnt[i];
    part[t] = s;
    __syncthreads();
    for (int d = 1; d < 1024; d <<= 1) {
        int v = part[t];
        int add = (t >= d) ? part[t - d] : 0;
        __syncthreads();
        part[t] = v + add;
        __syncthreads();
    }
    int off = (t == 0) ? 0 : part[t - 1];
    for (int i = lo; i < hi; ++i) { cursor[i] = off; off += cnt[i]; }
}

// After fill, cursor[v] == row_end(v); row_start = cursor[v] - cnt[v].
__global__ __launch_bounds__(256) void fill_adj(
    const int* __restrict__ src, const int* __restrict__ dst,
    int* __restrict__ cursor, int* __restrict__ adj, int E)
{
    int i = blockIdx.x * blockDim.x + threadIdx.x;
    if (i < E) {
        int pos = atomicAdd(&cursor[dst[i]], 1);
        adj[pos] = src[i];
    }
}

// ---------------- gather mean: agg[v] = mean_{u in N(v)} feat[u] --------
// One wave per dst node; lane owns CH float4s (CH = F/256).
template <int CH>
__global__ __launch_bounds__(256) void gather_mean(
    const float* __restrict__ feat, const int* __restrict__ adj,
    const int* __restrict__ cnt, const int* __restrict__ cursor,
    float* __restrict__ agg, int num_dst, int F)
{
    int wave = (blockIdx.x * blockDim.x + threadIdx.x) >> 6;
    int lane = threadIdx.x & 63;
    if (wave >= num_dst) return;
    int d = cnt[wave];
    int start = cursor[wave] - d;
    float4 acc[CH];
    #pragma unroll
    for (int c = 0; c < CH; ++c) acc[c] = make_float4(0.f, 0.f, 0.f, 0.f);
    for (int j = 0; j < d; ++j) {
        const float* fp = feat + (size_t)adj[start + j] * F;
        #pragma unroll
        for (int c = 0; c < CH; ++c) {
            float4 v = *(const float4*)(fp + (c << 8) + (lane << 2));
            acc[c].x += v.x; acc[c].y += v.y; acc[c].z += v.z; acc[c].w += v.w;
        }
    }
    float inv = 1.0f / (float)max(d, 1);
    float* ap = agg + (size_t)wave * F;
    #pragma unroll
    for (int c = 0; c < CH; ++c) {
        float4 v = make_float4(acc[c].x * inv, acc[c].y * inv,
                               acc[c].z * inv, acc[c].w * inv);
        *(float4*)(ap + (c << 8) + (lane << 2)) = v;
    }
}

// ---------------- fused dual-GEMM:  C = A1@W1 + A2@W2 + b ---------------
// 128x128 tile, BK=16, 256 threads, 8x8 per-thread (2x2 sub-blocks of 4).
// Requires: M % 128 == 0, N % 128 == 0, K % 16 == 0. (N=1024 here.)
__global__ __launch_bounds__(256, 2) void sage_gemm128(
    const float* __restrict__ A1, const float* __restrict__ A2,
    const float* __restrict__ W1, const float* __restrict__ W2,
    const float* __restrict__ bias, float* __restrict__ C,
    int M, int N, int K, int relu)
{
    __shared__ float As[16][132];   // [k][row]
    __shared__ float Wt[16][132];   // [k][col]

    const int tid  = threadIdx.x;
    const int row0 = blockIdx.x * 128;
    const int col0 = blockIdx.y * 128;
    const int tx = tid & 15;        // col group
    const int ty = tid >> 4;        // row group

    float acc[8][8];
    #pragma unroll
    for (int i = 0; i < 8; ++i)
        #pragma unroll
        for (int j = 0; j < 8; ++j) acc[i][j] = 0.0f;

    for (int pass = 0; pass < 2; ++pass) {
        const float* A = pass ? A2 : A1;
        const float* W = pass ? W2 : W1;
        for (int k0 = 0; k0 < K; k0 += 16) {
            #pragma unroll
            for (int q = 0; q < 2; ++q) {
                int f   = tid * 2 + q;
                int row = f >> 2;
                int kq  = (f & 3) << 2;
                float4 av = *(const float4*)(A + (size_t)(row0 + row) * K + k0 + kq);
                As[kq + 0][row] = av.x;
                As[kq + 1][row] = av.y;
                As[kq + 2][row] = av.z;
                As[kq + 3][row] = av.w;
            }
            #pragma unroll
            for (int q = 0; q < 2; ++q) {
                int f  = tid * 2 + q;
                int kk = f >> 5;
                int cq = (f & 31) << 2;
                float4 wv = *(const float4*)(W + (size_t)(k0 + kk) * N + col0 + cq);
                *(float4*)&Wt[kk][cq] = wv;
            }
            __syncthreads();
            #pragma unroll
            for (int k = 0; k < 16; ++k) {
                float4 a0 = *(const float4*)&As[k][ty << 2];
                float4 a1 = *(const float4*)&As[k][(ty << 2) + 64];
                float4 b0 = *(const float4*)&Wt[k][tx << 2];
                float4 b1 = *(const float4*)&Wt[k][(tx << 2) + 64];
                float ar[8] = {a0.x, a0.y, a0.z, a0.w, a1.x, a1.y, a1.z, a1.w};
                float br[8] = {b0.x, b0.y, b0.z, b0.w, b1.x, b1.y, b1.z, b1.w};
                #pragma unroll
                for (int i = 0; i < 8; ++i)
                    #pragma unroll
                    for (int j = 0; j < 8; ++j)
                        acc[i][j] = fmaf(ar[i], br[j], acc[i][j]);
            }
            __syncthreads();
        }
    }

    #pragma unroll
    for (int i = 0; i < 8; ++i) {
        int r = row0 + ((i < 4) ? ((ty << 2) + i) : (64 + (ty << 2) + i - 4));
        #pragma unroll
        for (int jh = 0; jh < 2; ++jh) {
            int c = col0 + (tx << 2) + jh * 64;
            float4 v;
            v.x = acc[i][jh * 4 + 0] + bias[c + 0];
            v.y = acc[i][jh * 4 + 1] + bias[c + 1];
            v.z = acc[i][jh * 4 + 2] + bias[c + 2];
            v.w = acc[i][jh * 4 + 3] + bias[c + 3];
            if (relu) {
                v.x = fmaxf(v.x, 0.0f); v.y = fmaxf(v.y, 0.0f);
                v.z = fmaxf(v.z, 0.0f); v.w = fmaxf(v.w, 0.0f);
            }
            *(float4*)(C + (size_t)r * N + c) = v;
        }
    }
}

// ---------------- skinny GEMM for the final [512 x 47] layer ------------
__global__ __launch_bounds__(256) void skinny_gemm(
    const float* __restrict__ A1, const float* __restrict__ A2,
    const float* __restrict__ W1, const float* __restrict__ W2,
    const float* __restrict__ bias, float* __restrict__ C,
    int M, int N, int K, int relu)
{
    int wave = (blockIdx.x * blockDim.x + threadIdx.x) >> 6;
    int lane = threadIdx.x & 63;
    if (wave >= M || lane >= N) return;
    const float* a1 = A1 + (size_t)wave * K;
    const float* a2 = A2 + (size_t)wave * K;
    float acc = 0.0f;
    #pragma unroll 8
    for (int k = 0; k < K; ++k) {
        acc = fmaf(a1[k], W1[(size_t)k * N + lane], acc);
        acc = fmaf(a2[k], W2[(size_t)k * N + lane], acc);
    }
    float v = acc + bias[lane];
    if (relu) v = fmaxf(v, 0.0f);
    C[(size_t)wave * N + lane] = v;
}

// ---------------- host side ---------------------------------------------
extern "C" void kernel_launch(void* const* d_in, const int* in_sizes, int n_in,
                              void* d_out, int out_size, void* d_ws, size_t ws_size,
                              hipStream_t stream)
{
    const float* x   = (const float*)d_in[0];
    const int* src0  = (const int*)d_in[1];
    const int* dst0  = (const int*)d_in[2];
    const int* src1  = (const int*)d_in[3];
    const int* dst1  = (const int*)d_in[4];
    const int* src2  = (const int*)d_in[5];
    const int* dst2  = (const int*)d_in[6];
    const float* Wself0  = (const float*)d_in[7];
    const float* Wneigh0 = (const float*)d_in[8];
    const float* b0      = (const float*)d_in[9];
    const float* Wself1  = (const float*)d_in[10];
    const float* Wneigh1 = (const float*)d_in[11];
    const float* b1      = (const float*)d_in[12];
    const float* Wself2  = (const float*)d_in[13];
    const float* Wneigh2 = (const float*)d_in[14];
    const float* b2      = (const float*)d_in[15];
    float* out = (float*)d_out;

    // ---- workspace carve-up ----
    float* ws = (float*)d_ws;
    size_t off = 0;
    float* h0   = ws + off; off += (size_t)NN1 * F_HID;   // 33792 x 1024
    float* h1   = ws + off; off += (size_t)NN2 * F_HID;   // 3072 x 1024
    float* agg0 = ws + off; off += (size_t)NN1 * F_IN;    // 33792 x 256 (mean)
    float* agg1 = ws + off; off += (size_t)NN2 * F_HID;   // 3072 x 1024
    float* agg2 = ws + off; off += (size_t)NN3 * F_HID;   // 512 x 1024
    int* iw = (int*)(ws + off);
    size_t ioff = 0;
    // cnt arrays contiguous -> single memset
    int* cnt0 = iw + ioff; ioff += NN1;
    int* cnt1 = iw + ioff; ioff += NN2;
    int* cnt2 = iw + ioff; ioff += NN3;
    size_t cnt_bytes = ioff * sizeof(int);
    int* cur0 = iw + ioff; ioff += NN1;
    int* cur1 = iw + ioff; ioff += NN2;
    int* cur2 = iw + ioff; ioff += NN3;
    int* adj0 = iw + ioff; ioff += E0;
    int* adj1 = iw + ioff; ioff += E1;
    int* adj2 = iw + ioff; ioff += E2;

    hipMemsetAsync(cnt0, 0, cnt_bytes, stream);

    // ---- Layer 0: CSR build + gather-mean + dual GEMM (K=256) ----
    count_dst<<<dim3((E0 + 255) / 256), dim3(256), 0, stream>>>(dst0, cnt0, E0);
    scan_excl<<<dim3(1), dim3(1024), 0, stream>>>(cnt0, cur0, NN1);
    fill_adj<<<dim3((E0 + 255) / 256), dim3(256), 0, stream>>>(src0, dst0, cur0, adj0, E0);
    gather_mean<1><<<dim3((NN1 + 3) / 4), dim3(256), 0, stream>>>(
        x, adj0, cnt0, cur0, agg0, NN1, F_IN);
    sage_gemm128<<<dim3(NN1 / 128, F_HID / 128), dim3(256), 0, stream>>>(
        x, agg0, Wself0, Wneigh0, b0, h0, NN1, F_HID, F_IN, 1);

    // ---- Layer 1 (K=1024) ----
    count_dst<<<dim3((E1 + 255) / 256), dim3(256), 0, stream>>>(dst1, cnt1, E1);
    scan_excl<<<dim3(1), dim3(1024), 0, stream>>>(cnt1, cur1, NN2);
    fill_adj<<<dim3((E1 + 255) / 256), dim3(256), 0, stream>>>(src1, dst1, cur1, adj1, E1);
    gather_mean<4><<<dim3((NN2 + 3) / 4), dim3(256), 0, stream>>>(
        h0, adj1, cnt1, cur1, agg1, NN2, F_HID);
    sage_gemm128<<<dim3(NN2 / 128, F_HID / 128), dim3(256), 0, stream>>>(
        h0, agg1, Wself1, Wneigh1, b1, h1, NN2, F_HID, F_HID, 1);

    // ---- Layer 2: [512, 2048] @ [2048, 47] -> d_out ----
    count_dst<<<dim3((E2 + 255) / 256), dim3(256), 0, stream>>>(dst2, cnt2, E2);
    scan_excl<<<dim3(1), dim3(1024), 0, stream>>>(cnt2, cur2, NN3);
    fill_adj<<<dim3((E2 + 255) / 256), dim3(256), 0, stream>>>(src2, dst2, cur2, adj2, E2);
    gather_mean<4><<<dim3((NN3 + 3) / 4), dim3(256), 0, stream>>>(
        h1, adj2, cnt2, cur2, agg2, NN3, F_HID);
    skinny_gemm<<<dim3(NN3 / 4), dim3(256), 0, stream>>>(
        h1, agg2, Wself2, Wneigh2, b2, out, NN3, F_OUT, F_HID, 0);
}

// Round 3
// 1006.370 us; speedup vs baseline: 3.6537x; 1.6325x over previous
//
#include <hip/hip_runtime.h>

// ---------------- problem constants (match setup_inputs) ----------------
#define E0 506880
#define E1 30720
#define E2 2560
#define NN0 540672
#define NN1 33792
#define NN2 3072
#define NN3 512
#define F_IN 256
#define F_HID 1024
#define F_OUT 47

typedef __attribute__((ext_vector_type(8))) short short8;  // 8 bf16 = 4 VGPRs
typedef __attribute__((ext_vector_type(4))) float f32x4;   // MFMA C/D frag

__device__ __forceinline__ float bf_lo(unsigned int u) {
    return __uint_as_float(u << 16);
}
__device__ __forceinline__ float bf_hi(unsigned int u) {
    return __uint_as_float(u & 0xFFFF0000u);
}
__device__ __forceinline__ unsigned short f2bf(float f) {
    unsigned int u = __float_as_uint(f);
    u = (u + 0x7FFFu + ((u >> 16) & 1u)) >> 16;   // RNE
    return (unsigned short)u;
}
__device__ __forceinline__ unsigned int pack2(float a, float b) {
    return (unsigned int)f2bf(a) | ((unsigned int)f2bf(b) << 16);
}

// ---------------- CSR build: counting sort of edges by dst --------------
__global__ __launch_bounds__(256) void count_dst(
    const int* __restrict__ dst, int* __restrict__ cnt, int E)
{
    int i = blockIdx.x * blockDim.x + threadIdx.x;
    if (i < E) atomicAdd(&cnt[dst[i]], 1);
}

__global__ __launch_bounds__(1024) void scan_excl(
    const int* __restrict__ cnt, int* __restrict__ cursor, int n)
{
    __shared__ int part[1024];
    int t = threadIdx.x;
    int per = (n + 1023) >> 10;
    int lo = t * per;
    int hi = min(n, lo + per);
    int s = 0;
    for (int i = lo; i < hi; ++i) s += cnt[i];
    part[t] = s;
    __syncthreads();
    for (int d = 1; d < 1024; d <<= 1) {
        int v = part[t];
        int add = (t >= d) ? part[t - d] : 0;
        __syncthreads();
        part[t] = v + add;
        __syncthreads();
    }
    int off = (t == 0) ? 0 : part[t - 1];
    for (int i = lo; i < hi; ++i) { cursor[i] = off; off += cnt[i]; }
}

// After fill, cursor[v] == row_end(v); row_start = cursor[v] - cnt[v].
__global__ __launch_bounds__(256) void fill_adj(
    const int* __restrict__ src, const int* __restrict__ dst,
    int* __restrict__ cursor, int* __restrict__ adj, int E)
{
    int i = blockIdx.x * blockDim.x + threadIdx.x;
    if (i < E) {
        int pos = atomicAdd(&cursor[dst[i]], 1);
        adj[pos] = src[i];
    }
}

// ---------------- dtype conversions -------------------------------------
// fp32 -> bf16, 8 elems/thread
__global__ __launch_bounds__(256) void cast_f32_bf16(
    const float* __restrict__ in, unsigned short* __restrict__ out, int n8)
{
    int i = blockIdx.x * blockDim.x + threadIdx.x;
    if (i >= n8) return;
    float4 a = *(const float4*)(in + (size_t)i * 8);
    float4 b = *(const float4*)(in + (size_t)i * 8 + 4);
    uint4 o;
    o.x = pack2(a.x, a.y); o.y = pack2(a.z, a.w);
    o.z = pack2(b.x, b.y); o.w = pack2(b.z, b.w);
    *(uint4*)(out + (size_t)i * 8) = o;
}

// W fp32 [K][N] -> Wt bf16 [N][K], 32x32 LDS tile transpose
__global__ __launch_bounds__(256) void transpose_cast(
    const float* __restrict__ W, unsigned short* __restrict__ Wt, int K, int N)
{
    __shared__ float t[32][33];
    int k0 = blockIdx.x * 32;
    int n0 = blockIdx.y * 32;
    int tx = threadIdx.x & 31;
    int ty = threadIdx.x >> 5;   // 0..7
    #pragma unroll
    for (int i = 0; i < 4; ++i) {
        int r = ty * 4 + i;
        t[r][tx] = W[(size_t)(k0 + r) * N + n0 + tx];
    }
    __syncthreads();
    #pragma unroll
    for (int i = 0; i < 4; ++i) {
        int nr = ty * 4 + i;
        Wt[(size_t)(n0 + nr) * K + k0 + tx] = f2bf(t[tx][nr]);
    }
}

// ---------------- gather mean (fp32 feat, F=256) -> bf16 ----------------
__global__ __launch_bounds__(256) void gather_mean_f32(
    const float* __restrict__ feat, const int* __restrict__ adj,
    const int* __restrict__ cnt, const int* __restrict__ cur,
    unsigned short* __restrict__ agg, int num_dst)
{
    int wave = (blockIdx.x * blockDim.x + threadIdx.x) >> 6;
    int lane = threadIdx.x & 63;
    if (wave >= num_dst) return;
    int d = cnt[wave];
    int start = cur[wave] - d;
    float4 a0 = make_float4(0.f, 0.f, 0.f, 0.f), a1 = a0, a2 = a0, a3 = a0;
    int j = 0;
    for (; j + 3 < d; j += 4) {
        int i0 = adj[start + j + 0], i1 = adj[start + j + 1];
        int i2 = adj[start + j + 2], i3 = adj[start + j + 3];
        float4 v0 = *(const float4*)(feat + (size_t)i0 * F_IN + lane * 4);
        float4 v1 = *(const float4*)(feat + (size_t)i1 * F_IN + lane * 4);
        float4 v2 = *(const float4*)(feat + (size_t)i2 * F_IN + lane * 4);
        float4 v3 = *(const float4*)(feat + (size_t)i3 * F_IN + lane * 4);
        a0.x += v0.x; a0.y += v0.y; a0.z += v0.z; a0.w += v0.w;
        a1.x += v1.x; a1.y += v1.y; a1.z += v1.z; a1.w += v1.w;
        a2.x += v2.x; a2.y += v2.y; a2.z += v2.z; a2.w += v2.w;
        a3.x += v3.x; a3.y += v3.y; a3.z += v3.z; a3.w += v3.w;
    }
    for (; j < d; ++j) {
        int i0 = adj[start + j];
        float4 v0 = *(const float4*)(feat + (size_t)i0 * F_IN + lane * 4);
        a0.x += v0.x; a0.y += v0.y; a0.z += v0.z; a0.w += v0.w;
    }
    float inv = 1.0f / (float)(d > 0 ? d : 1);
    float sx = (a0.x + a1.x) + (a2.x + a3.x);
    float sy = (a0.y + a1.y) + (a2.y + a3.y);
    float sz = (a0.z + a1.z) + (a2.z + a3.z);
    float sw = (a0.w + a1.w) + (a2.w + a3.w);
    uint2 o;
    o.x = pack2(sx * inv, sy * inv);
    o.y = pack2(sz * inv, sw * inv);
    *(uint2*)(agg + (size_t)wave * F_IN + lane * 4) = o;
}

// ---------------- gather mean (bf16 feat, F=1024) -> bf16 ---------------
__global__ __launch_bounds__(256) void gather_mean_bf16(
    const unsigned short* __restrict__ feat, const int* __restrict__ adj,
    const int* __restrict__ cnt, const int* __restrict__ cur,
    unsigned short* __restrict__ agg, int num_dst)
{
    int wave = (blockIdx.x * blockDim.x + threadIdx.x) >> 6;
    int lane = threadIdx.x & 63;
    if (wave >= num_dst) return;
    int d = cnt[wave];
    int start = cur[wave] - d;
    float acc[16];
    #pragma unroll
    for (int c = 0; c < 16; ++c) acc[c] = 0.f;
    int j = 0;
    for (; j + 1 < d; j += 2) {
        const unsigned short* f0 = feat + (size_t)adj[start + j] * F_HID + lane * 16;
        const unsigned short* f1 = feat + (size_t)adj[start + j + 1] * F_HID + lane * 16;
        uint4 p0 = *(const uint4*)f0;
        uint4 p1 = *(const uint4*)(f0 + 8);
        uint4 q0 = *(const uint4*)f1;
        uint4 q1 = *(const uint4*)(f1 + 8);
        acc[0] += bf_lo(p0.x); acc[1] += bf_hi(p0.x);
        acc[2] += bf_lo(p0.y); acc[3] += bf_hi(p0.y);
        acc[4] += bf_lo(p0.z); acc[5] += bf_hi(p0.z);
        acc[6] += bf_lo(p0.w); acc[7] += bf_hi(p0.w);
        acc[8]  += bf_lo(p1.x); acc[9]  += bf_hi(p1.x);
        acc[10] += bf_lo(p1.y); acc[11] += bf_hi(p1.y);
        acc[12] += bf_lo(p1.z); acc[13] += bf_hi(p1.z);
        acc[14] += bf_lo(p1.w); acc[15] += bf_hi(p1.w);
        acc[0] += bf_lo(q0.x); acc[1] += bf_hi(q0.x);
        acc[2] += bf_lo(q0.y); acc[3] += bf_hi(q0.y);
        acc[4] += bf_lo(q0.z); acc[5] += bf_hi(q0.z);
        acc[6] += bf_lo(q0.w); acc[7] += bf_hi(q0.w);
        acc[8]  += bf_lo(q1.x); acc[9]  += bf_hi(q1.x);
        acc[10] += bf_lo(q1.y); acc[11] += bf_hi(q1.y);
        acc[12] += bf_lo(q1.z); acc[13] += bf_hi(q1.z);
        acc[14] += bf_lo(q1.w); acc[15] += bf_hi(q1.w);
    }
    if (j < d) {
        const unsigned short* f0 = feat + (size_t)adj[start + j] * F_HID + lane * 16;
        uint4 p0 = *(const uint4*)f0;
        uint4 p1 = *(const uint4*)(f0 + 8);
        acc[0] += bf_lo(p0.x); acc[1] += bf_hi(p0.x);
        acc[2] += bf_lo(p0.y); acc[3] += bf_hi(p0.y);
        acc[4] += bf_lo(p0.z); acc[5] += bf_hi(p0.z);
        acc[6] += bf_lo(p0.w); acc[7] += bf_hi(p0.w);
        acc[8]  += bf_lo(p1.x); acc[9]  += bf_hi(p1.x);
        acc[10] += bf_lo(p1.y); acc[11] += bf_hi(p1.y);
        acc[12] += bf_lo(p1.z); acc[13] += bf_hi(p1.z);
        acc[14] += bf_lo(p1.w); acc[15] += bf_hi(p1.w);
    }
    float inv = 1.0f / (float)(d > 0 ? d : 1);
    uint4 o0, o1;
    o0.x = pack2(acc[0] * inv, acc[1] * inv);
    o0.y = pack2(acc[2] * inv, acc[3] * inv);
    o0.z = pack2(acc[4] * inv, acc[5] * inv);
    o0.w = pack2(acc[6] * inv, acc[7] * inv);
    o1.x = pack2(acc[8] * inv, acc[9] * inv);
    o1.y = pack2(acc[10] * inv, acc[11] * inv);
    o1.z = pack2(acc[12] * inv, acc[13] * inv);
    o1.w = pack2(acc[14] * inv, acc[15] * inv);
    unsigned short* ap = agg + (size_t)wave * F_HID + lane * 16;
    *(uint4*)ap = o0;
    *(uint4*)(ap + 8) = o1;
}

// ---------------- bf16 MFMA dual-GEMM: C = A1@W1^T' + A2@W2^T' + b ------
// A: bf16 [M][K] row-major.  Wt: bf16 [N][K] (pre-transposed).  C: bf16 [M][N].
// 128x128 tile, BK=32, 256 threads = 4 waves (2x2), each wave 64x64 (4x4 MFMA
// tiles of 16x16x32). LDS rows padded to 40 bf16 (80 B) for 16B-aligned b128.
__global__ __launch_bounds__(256, 2) void sage_mfma_gemm(
    const unsigned short* __restrict__ A1, const unsigned short* __restrict__ A2,
    const unsigned short* __restrict__ Wt1, const unsigned short* __restrict__ Wt2,
    const float* __restrict__ bias, unsigned short* __restrict__ C,
    int M, int N, int K, int relu)
{
    __shared__ __align__(16) unsigned short As[128 * 40];
    __shared__ __align__(16) unsigned short Bs[128 * 40];

    const int tid  = threadIdx.x;
    const int wave = tid >> 6;
    const int lane = tid & 63;
    const int wy = wave >> 1, wx = wave & 1;
    const int quad = lane >> 4, l16 = lane & 15;
    const int col0 = blockIdx.x * 128;   // x = col-block (few) -> A reuse in L2/L3
    const int row0 = blockIdx.y * 128;   // y = row-block (many)

    f32x4 acc[4][4];
    #pragma unroll
    for (int i = 0; i < 4; ++i)
        #pragma unroll
        for (int j = 0; j < 4; ++j)
            acc[i][j] = (f32x4){0.f, 0.f, 0.f, 0.f};

    for (int pass = 0; pass < 2; ++pass) {
        const unsigned short* A  = pass ? A2  : A1;
        const unsigned short* Wt = pass ? Wt2 : Wt1;
        for (int k0 = 0; k0 < K; k0 += 32) {
            // stage A tile: 128 rows x 32 k = 512 16B-chunks, 2/thread.
            // f = tid + q*256: lanes 0..3 cover one row's 64B contiguously.
            #pragma unroll
            for (int q = 0; q < 2; ++q) {
                int f = tid + q * 256;
                int r = f >> 2, kq = (f & 3) * 8;
                float4 v = *(const float4*)(A + (size_t)(row0 + r) * K + k0 + kq);
                *(float4*)(&As[r * 40 + kq]) = v;
            }
            // stage B tile from Wt[n][k]: identical mapping (n instead of row)
            #pragma unroll
            for (int q = 0; q < 2; ++q) {
                int f = tid + q * 256;
                int n = f >> 2, kq = (f & 3) * 8;
                float4 v = *(const float4*)(Wt + (size_t)(col0 + n) * K + k0 + kq);
                *(float4*)(&Bs[n * 40 + kq]) = v;
            }
            __syncthreads();
            short8 af[4], bfr[4];
            #pragma unroll
            for (int mi = 0; mi < 4; ++mi)
                af[mi] = *(const short8*)(&As[(wy * 64 + mi * 16 + l16) * 40 + quad * 8]);
            #pragma unroll
            for (int ni = 0; ni < 4; ++ni)
                bfr[ni] = *(const short8*)(&Bs[(wx * 64 + ni * 16 + l16) * 40 + quad * 8]);
            #pragma unroll
            for (int mi = 0; mi < 4; ++mi)
                #pragma unroll
                for (int ni = 0; ni < 4; ++ni)
                    acc[mi][ni] = __builtin_amdgcn_mfma_f32_16x16x32_bf16(
                        af[mi], bfr[ni], acc[mi][ni], 0, 0, 0);
            __syncthreads();
        }
    }

    // epilogue: C/D layout col=lane&15, row=quad*4+reg
    #pragma unroll
    for (int ni = 0; ni < 4; ++ni) {
        int col = col0 + wx * 64 + ni * 16 + l16;
        float bc = bias[col];
        #pragma unroll
        for (int mi = 0; mi < 4; ++mi) {
            int row = row0 + wy * 64 + mi * 16 + quad * 4;
            #pragma unroll
            for (int r = 0; r < 4; ++r) {
                float v = acc[mi][ni][r] + bc;
                if (relu) v = fmaxf(v, 0.0f);
                C[(size_t)(row + r) * N + col] = f2bf(v);
            }
        }
    }
}

// ---------------- skinny GEMM for the final [512 x 47] layer ------------
// Block per output row; 4 waves split K; LDS reduce; fp32 weights & output.
__global__ __launch_bounds__(256) void skinny_gemm_blk(
    const unsigned short* __restrict__ A1, const unsigned short* __restrict__ A2,
    const float* __restrict__ W1, const float* __restrict__ W2,
    const float* __restrict__ bias, float* __restrict__ C, int K)
{
    __shared__ float red[4][64];
    int m = blockIdx.x;
    int wave = threadIdx.x >> 6;
    int lane = threadIdx.x & 63;
    const unsigned short* a1 = A1 + (size_t)m * K;
    const unsigned short* a2 = A2 + (size_t)m * K;
    float acc = 0.f;
    if (lane < F_OUT) {
        int kb = wave * (K >> 2), ke = kb + (K >> 2);
        #pragma unroll 8
        for (int k = kb; k < ke; ++k) {
            acc = fmaf(bf_lo((unsigned int)a1[k]), W1[(size_t)k * F_OUT + lane], acc);
            acc = fmaf(bf_lo((unsigned int)a2[k]), W2[(size_t)k * F_OUT + lane], acc);
        }
    }
    red[wave][lane] = acc;
    __syncthreads();
    if (wave == 0 && lane < F_OUT) {
        float v = (red[0][lane] + red[1][lane]) + (red[2][lane] + red[3][lane])
                + bias[lane];
        C[(size_t)m * F_OUT + lane] = v;
    }
}

// ---------------- host side ---------------------------------------------
extern "C" void kernel_launch(void* const* d_in, const int* in_sizes, int n_in,
                              void* d_out, int out_size, void* d_ws, size_t ws_size,
                              hipStream_t stream)
{
    const float* x   = (const float*)d_in[0];
    const int* src0  = (const int*)d_in[1];
    const int* dst0  = (const int*)d_in[2];
    const int* src1  = (const int*)d_in[3];
    const int* dst1  = (const int*)d_in[4];
    const int* src2  = (const int*)d_in[5];
    const int* dst2  = (const int*)d_in[6];
    const float* Wself0  = (const float*)d_in[7];
    const float* Wneigh0 = (const float*)d_in[8];
    const float* b0      = (const float*)d_in[9];
    const float* Wself1  = (const float*)d_in[10];
    const float* Wneigh1 = (const float*)d_in[11];
    const float* b1      = (const float*)d_in[12];
    const float* Wself2  = (const float*)d_in[13];
    const float* Wneigh2 = (const float*)d_in[14];
    const float* b2      = (const float*)d_in[15];
    float* out = (float*)d_out;

    // ---- workspace carve-up (bytes, 256B-aligned chunks) ----
    char* base = (char*)d_ws;
    auto alloc = [&](size_t bytes) -> char* {
        char* p = base;
        base += (bytes + 255) & ~(size_t)255;
        return p;
    };
    unsigned short* h0   = (unsigned short*)alloc((size_t)NN1 * F_HID * 2);
    unsigned short* h1   = (unsigned short*)alloc((size_t)NN2 * F_HID * 2);
    unsigned short* agg0 = (unsigned short*)alloc((size_t)NN1 * F_IN * 2);
    unsigned short* agg1 = (unsigned short*)alloc((size_t)NN2 * F_HID * 2);
    unsigned short* agg2 = (unsigned short*)alloc((size_t)NN3 * F_HID * 2);
    unsigned short* xbf  = (unsigned short*)alloc((size_t)NN1 * F_IN * 2);
    unsigned short* Wt0s = (unsigned short*)alloc((size_t)F_HID * F_IN * 2);
    unsigned short* Wt0n = (unsigned short*)alloc((size_t)F_HID * F_IN * 2);
    unsigned short* Wt1s = (unsigned short*)alloc((size_t)F_HID * F_HID * 2);
    unsigned short* Wt1n = (unsigned short*)alloc((size_t)F_HID * F_HID * 2);
    int* cnt0 = (int*)alloc((size_t)(NN1 + NN2 + NN3) * 4);   // contiguous
    int* cnt1 = cnt0 + NN1;
    int* cnt2 = cnt1 + NN2;
    int* cur0 = (int*)alloc((size_t)NN1 * 4);
    int* cur1 = (int*)alloc((size_t)NN2 * 4);
    int* cur2 = (int*)alloc((size_t)NN3 * 4);
    int* adj0 = (int*)alloc((size_t)E0 * 4);
    int* adj1 = (int*)alloc((size_t)E1 * 4);
    int* adj2 = (int*)alloc((size_t)E2 * 4);

    hipMemsetAsync(cnt0, 0, (size_t)(NN1 + NN2 + NN3) * 4, stream);

    // ---- prep: casts / weight transposes (independent of CSR) ----
    int n8 = NN1 * F_IN / 8;
    cast_f32_bf16<<<dim3((n8 + 255) / 256), dim3(256), 0, stream>>>(x, xbf, n8);
    transpose_cast<<<dim3(F_IN / 32, F_HID / 32), dim3(256), 0, stream>>>(
        Wself0, Wt0s, F_IN, F_HID);
    transpose_cast<<<dim3(F_IN / 32, F_HID / 32), dim3(256), 0, stream>>>(
        Wneigh0, Wt0n, F_IN, F_HID);
    transpose_cast<<<dim3(F_HID / 32, F_HID / 32), dim3(256), 0, stream>>>(
        Wself1, Wt1s, F_HID, F_HID);
    transpose_cast<<<dim3(F_HID / 32, F_HID / 32), dim3(256), 0, stream>>>(
        Wneigh1, Wt1n, F_HID, F_HID);

    // ---- CSR builds ----
    count_dst<<<dim3((E0 + 255) / 256), dim3(256), 0, stream>>>(dst0, cnt0, E0);
    count_dst<<<dim3((E1 + 255) / 256), dim3(256), 0, stream>>>(dst1, cnt1, E1);
    count_dst<<<dim3((E2 + 255) / 256), dim3(256), 0, stream>>>(dst2, cnt2, E2);
    scan_excl<<<dim3(1), dim3(1024), 0, stream>>>(cnt0, cur0, NN1);
    scan_excl<<<dim3(1), dim3(1024), 0, stream>>>(cnt1, cur1, NN2);
    scan_excl<<<dim3(1), dim3(1024), 0, stream>>>(cnt2, cur2, NN3);
    fill_adj<<<dim3((E0 + 255) / 256), dim3(256), 0, stream>>>(src0, dst0, cur0, adj0, E0);
    fill_adj<<<dim3((E1 + 255) / 256), dim3(256), 0, stream>>>(src1, dst1, cur1, adj1, E1);
    fill_adj<<<dim3((E2 + 255) / 256), dim3(256), 0, stream>>>(src2, dst2, cur2, adj2, E2);

    // ---- Layer 0: gather-mean (fp32 x) + bf16 MFMA dual-GEMM (K=256) ----
    gather_mean_f32<<<dim3(NN1 / 4), dim3(256), 0, stream>>>(
        x, adj0, cnt0, cur0, agg0, NN1);
    sage_mfma_gemm<<<dim3(F_HID / 128, NN1 / 128), dim3(256), 0, stream>>>(
        xbf, agg0, Wt0s, Wt0n, b0, h0, NN1, F_HID, F_IN, 1);

    // ---- Layer 1 (K=1024) ----
    gather_mean_bf16<<<dim3(NN2 / 4), dim3(256), 0, stream>>>(
        h0, adj1, cnt1, cur1, agg1, NN2);
    sage_mfma_gemm<<<dim3(F_HID / 128, NN2 / 128), dim3(256), 0, stream>>>(
        h0, agg1, Wt1s, Wt1n, b1, h1, NN2, F_HID, F_HID, 1);

    // ---- Layer 2: [512, 2x1024] @ [2x1024, 47] -> d_out (fp32) ----
    gather_mean_bf16<<<dim3(NN3 / 4), dim3(256), 0, stream>>>(
        h1, adj2, cnt2, cur2, agg2, NN3);
    skinny_gemm_blk<<<dim3(NN3), dim3(256), 0, stream>>>(
        h1, agg2, Wself2, Wneigh2, b2, out, F_HID);
}